// Round 3
// baseline (7486.147 us; speedup 1.0000x reference)
//
#include <hip/hip_runtime.h>
#include <hip/hip_bf16.h>
#include <cstdint>
#include <cstddef>

#define B_   64
#define CIN  1024
#define L_   1024
#define T_   64
#define Hh_  256
#define Dd_  256
#define Cc_  111
#define NO_  512
#define KX_  623
#define NSUB 8
#define LSUB 128

typedef __attribute__((ext_vector_type(8))) short short8;
typedef __attribute__((ext_vector_type(4))) float floatx4;

__device__ __forceinline__ float bf2f(unsigned short u) {
    union { unsigned int i; float f; } v; v.i = ((unsigned int)u) << 16; return v.f;
}
__device__ __forceinline__ unsigned short f2bf(float f) {
    union { float f; unsigned int i; } v; v.f = f;
    return (unsigned short)((v.i + 0x7fffu + ((v.i >> 16) & 1u)) >> 16);
}
__device__ __forceinline__ float frcp(float x) { return __builtin_amdgcn_rcpf(x); }
__device__ __forceinline__ float tanh_fast(float x) {
    return 1.0f - 2.0f * frcp(1.0f + __expf(2.0f * x));
}
__device__ __forceinline__ float sig_fast(float x) {
    return frcp(1.0f + __expf(-x));
}

// ---------------- prep kernels ----------------

__global__ void pe_kernel(float* __restrict__ PE) {
    int idx = blockIdx.x * 256 + threadIdx.x;
    if (idx >= L_ * NO_) return;
    int l = idx >> 9, j = idx & 511;
    int i2 = j & ~1;
    float div = expf((float)i2 * (-9.210340371976184f / 512.0f));
    float arg = (float)l * div;
    PE[idx] = (j & 1) ? cosf(arg) : sinf(arg);
}

__global__ void wc_kernel(const float* __restrict__ conv_w,
                          const float* __restrict__ attn_w,
                          unsigned short* __restrict__ Wc) {
    int c = blockIdx.x * 256 + threadIdx.x;
    int o = blockIdx.y;
    float v;
    if (o < 256) {
        v = conv_w[(size_t)o * CIN + c];
    } else {
        const float* aw = attn_w + (size_t)(o - 256) * 512;
        float a = 0.0f;
        for (int d = 0; d < 512; ++d)
            a = fmaf(aw[d], conv_w[(size_t)d * CIN + c], a);
        v = a;
    }
    Wc[(size_t)o * CIN + c] = f2bf(v);
}

__global__ void biasf_kernel(const float* __restrict__ conv_b,
                             const float* __restrict__ PE,
                             float* __restrict__ biasC) {
    int idx = blockIdx.x * 256 + threadIdx.x;
    int l = idx >> 8, j = idx & 255;
    biasC[(size_t)l * NO_ + j] = conv_b[j] + PE[(size_t)l * NO_ + j];
}

__global__ void biasw_kernel(const float* __restrict__ conv_b,
                             const float* __restrict__ PE,
                             const float* __restrict__ attn_w,
                             const float* __restrict__ attn_b,
                             float* __restrict__ biasC) {
    int l = blockIdx.x * 256 + threadIdx.x;
    int h = blockIdx.y;
    const float* aw = attn_w + (size_t)h * 512;
    const float* pe = PE + (size_t)l * NO_;
    float a = 0.0f;
    for (int d = 0; d < 512; ++d)
        a = fmaf(aw[d], conv_b[d] + pe[d], a);
    biasC[(size_t)l * NO_ + 256 + h] = a + attn_b[h];
}

__global__ void wiht_kernel(const float* __restrict__ wih, unsigned short* __restrict__ WihT) {
    int idx = blockIdx.x * 256 + threadIdx.x;
    if (idx >= 768 * KX_) return;
    int o = idx / KX_, k = idx - o * KX_;
    WihT[(size_t)k * 768 + o] = f2bf(wih[idx]);
}
__global__ void whht_kernel(const float* __restrict__ whh, unsigned short* __restrict__ WhhT) {
    int idx = blockIdx.x * 256 + threadIdx.x;
    if (idx >= 768 * 256) return;
    int o = idx >> 8, k = idx & 255;
    WhhT[(size_t)k * 768 + o] = f2bf(whh[idx]);
}
__global__ void woutt_kernel(const float* __restrict__ outw, unsigned short* __restrict__ WoutT) {
    int idx = blockIdx.x * 256 + threadIdx.x;
    if (idx >= Cc_ * KX_) return;
    int c = idx / KX_, k = idx - c * KX_;
    WoutT[(size_t)k * 128 + c] = f2bf(outw[idx]);
}

__global__ void zero_kernel(int* __restrict__ p, int n) {
    int i = blockIdx.x * 256 + threadIdx.x;
    if (i < n) p[i] = 0;
}

// ---------------- fused conv+projection GEMM ----------------
__global__ __launch_bounds__(256) void gemm_feats(
    const float* __restrict__ fm,
    const unsigned short* __restrict__ Wc,
    const float* __restrict__ biasC,
    unsigned short* __restrict__ F) {
    __shared__ __align__(16) unsigned short Als[128 * 40];
    __shared__ __align__(16) unsigned short Bls[128 * 40];
    const int tid  = threadIdx.x;
    const int bx   = blockIdx.x;
    const int bb   = bx >> 3;
    const int l0   = (bx & 7) << 7;
    const int n0   = blockIdx.y << 7;
    const int wid  = tid >> 6;
    const int lane = tid & 63;
    const int m0w  = (wid & 1) << 6;
    const int n0w  = (wid >> 1) << 6;
    const int quad = lane >> 4;
    const int l16  = lane & 15;

    floatx4 acc[4][4];
#pragma unroll
    for (int i = 0; i < 4; ++i)
#pragma unroll
        for (int j = 0; j < 4; ++j)
            acc[i][j] = (floatx4){0.f, 0.f, 0.f, 0.f};

    const int lt    = tid & 127;
    const int chalf = tid >> 7;
    const float* fmb = fm + ((size_t)bb * CIN) * L_ + l0 + lt;
    const int bo = tid >> 2;
    const int bc = (tid & 3) << 3;
    const int swzA = ((lt >> 2) & 3) << 3;

    for (int kk = 0; kk < 32; ++kk) {
        const int c0 = kk << 5;
        __syncthreads();
#pragma unroll
        for (int i = 0; i < 8; ++i) {
            int cc = (chalf + (i << 1)) << 1;
            float v0 = fmb[(size_t)(c0 + cc) * L_];
            float v1 = fmb[(size_t)(c0 + cc + 1) * L_];
            unsigned int pk = (unsigned int)f2bf(v0) | ((unsigned int)f2bf(v1) << 16);
            *(unsigned int*)(&Als[lt * 40 + (cc ^ swzA)]) = pk;
        }
#pragma unroll
        for (int i = 0; i < 2; ++i) {
            int o = bo + (i << 6);
            uint4 w = *(const uint4*)(&Wc[(size_t)(n0 + o) * CIN + c0 + bc]);
            *(uint4*)(&Bls[o * 40 + bc]) = w;
        }
        __syncthreads();
        short8 afr[4], bfr[4];
#pragma unroll
        for (int mf = 0; mf < 4; ++mf) {
            int mm = m0w + (mf << 4) + l16;
            int k0 = (quad << 3) ^ (((mm >> 2) & 3) << 3);
            afr[mf] = *(const short8*)(&Als[mm * 40 + k0]);
        }
#pragma unroll
        for (int nf = 0; nf < 4; ++nf) {
            int nn = n0w + (nf << 4) + l16;
            bfr[nf] = *(const short8*)(&Bls[nn * 40 + (quad << 3)]);
        }
#pragma unroll
        for (int mf = 0; mf < 4; ++mf)
#pragma unroll
            for (int nf = 0; nf < 4; ++nf)
                acc[mf][nf] = __builtin_amdgcn_mfma_f32_16x16x32_bf16(afr[mf], bfr[nf], acc[mf][nf], 0, 0, 0);
    }

#pragma unroll
    for (int mf = 0; mf < 4; ++mf) {
#pragma unroll
        for (int nf = 0; nf < 4; ++nf) {
            int colg = n0 + n0w + (nf << 4) + l16;
#pragma unroll
            for (int r = 0; r < 4; ++r) {
                int lb = l0 + m0w + (mf << 4) + (quad << 2) + r;
                float v = acc[mf][nf][r] + biasC[(size_t)lb * NO_ + colg];
                F[((size_t)bb * L_ + lb) * NO_ + colg] = f2bf(v);
            }
        }
    }
}

// ---------------- decoder: 8 blocks per batch ----------------

__device__ __forceinline__ void batch_barrier(int* bar, int target, int tid) {
    __syncthreads();
    if (tid == 0) {
        __hip_atomic_fetch_add(bar, 1, __ATOMIC_RELEASE, __HIP_MEMORY_SCOPE_AGENT);
        while (__hip_atomic_load(bar, __ATOMIC_ACQUIRE, __HIP_MEMORY_SCOPE_AGENT) < target) {
            __builtin_amdgcn_s_sleep(2);
        }
    }
    __syncthreads();
}

__global__ __launch_bounds__(1024, 8) void decoder_kernel(
    const unsigned short* __restrict__ F,
    const unsigned short* __restrict__ WihT,
    const unsigned short* __restrict__ WhhT,
    const unsigned short* __restrict__ WoutT,
    const float* __restrict__ cvv,
    const int* __restrict__ tgt,
    const float* __restrict__ emb,
    const float* __restrict__ bih,
    const float* __restrict__ bhh,
    const float* __restrict__ attn_v,
    const float* __restrict__ attn_vb,
    const float* __restrict__ cov_w,
    const float* __restrict__ cov_b,
    const float* __restrict__ outb,
    int* __restrict__ bar,
    float* __restrict__ gsum,
    float* __restrict__ gctx,
    float* __restrict__ ggih,
    float* __restrict__ OUT) {
    __shared__ float sc[LSUB];
    __shared__ float cov[LSUB];
    __shared__ float xv[640];
    __shared__ float xo[640];
    __shared__ float hv[256];
    __shared__ float hbs[256];
    __shared__ float gi[768];
    __shared__ float gh[768];
    __shared__ float ctxp[32 * 256];
    __shared__ float outp[64 * 16];
    __shared__ float red[32];

    const int tid  = threadIdx.x;
    const int bx   = blockIdx.x;
    const int b    = bx >> 3;
    const int sub  = bx & 7;
    const int l0   = sub << 7;
    const int lane = tid & 63;
    const int wid  = tid >> 6;

    int*   mybar = bar + b * 16;
    float* myctx = gctx + (size_t)b * NSUB * 256;
    float* mysum = gsum + b * NSUB;
    float* mygg  = ggih + (size_t)b * NSUB * 1536;

    if (tid < LSUB) cov[tid] = 0.0f;
    if (tid < 256) { hv[tid] = 0.0f; hbs[tid] = cov_b[tid]; }
    if (tid >= 512 && tid < 512 + Cc_) xv[tid] = cvv[b * Cc_ + (tid - 512)];

    // score-pass constants: 8 h per lane (32 lanes per l)
    const int hh0 = (lane & 31) << 3;
    float cw_r[8], av_r[8];
#pragma unroll
    for (int i = 0; i < 8; ++i) { cw_r[i] = cov_w[hh0 + i]; av_r[i] = attn_v[hh0 + i]; }
    const float avb = attn_vb[0];

    const int kg0   = sub * 78;
    const int kg1   = (kg0 + 78 > KX_) ? KX_ : kg0 + 78;
    const int kh0   = sub << 5;
    const int cbase = sub * 14;
    const int ccnt  = (sub == 7) ? 13 : 14;

    const int lpair = ((tid >> 6) << 1) + (lane >> 5);  // 0..31

    int nsync = 0;
    __syncthreads();

    for (int t = 0; t < T_; ++t) {
        // embedded token
        if (tid < 256) {
            int ytok = (t == 0) ? 1 : tgt[b * T_ + t - 1];
            xv[tid] = emb[ytok * Dd_ + tid];
        }
        float hb_r[8];
        *(float4*)&hb_r[0] = *(const float4*)&hbs[hh0];
        *(float4*)&hb_r[4] = *(const float4*)&hbs[hh0 + 4];

        // ---- attention scores: 4 passes x (32 l x 32 lanes), preloaded uint4 ----
        uint4  wv[4];
        float  cv4[4];
#pragma unroll
        for (int p = 0; p < 4; ++p) {
            int ll = (p << 5) + lpair;
            const unsigned short* wf = F + (((size_t)(b * L_ + l0 + ll)) << 9) + Hh_ + hh0;
            wv[p]  = *(const uint4*)wf;
            cv4[p] = cov[ll];
        }
#pragma unroll
        for (int p = 0; p < 4; ++p) {
            int ll = (p << 5) + lpair;
            float covl = cv4[p];
            unsigned int wsx[4] = {wv[p].x, wv[p].y, wv[p].z, wv[p].w};
            float a = 0.0f;
#pragma unroll
            for (int q = 0; q < 4; ++q) {
                float g0 = bf2f((unsigned short)(wsx[q] & 0xffffu)) + fmaf(covl, cw_r[2 * q],     hb_r[2 * q]);
                float g1 = bf2f((unsigned short)(wsx[q] >> 16))     + fmaf(covl, cw_r[2 * q + 1], hb_r[2 * q + 1]);
                a = fmaf(av_r[2 * q],     tanh_fast(g0), a);
                a = fmaf(av_r[2 * q + 1], tanh_fast(g1), a);
            }
            a += __shfl_xor(a, 1);
            a += __shfl_xor(a, 2);
            a += __shfl_xor(a, 4);
            a += __shfl_xor(a, 8);
            a += __shfl_xor(a, 16);
            if ((lane & 31) == 0) sc[ll] = __expf(a + avb);
        }
        __syncthreads();

        // ---- local exp-sum (waves 0-1) ----
        if (tid < 128) {
            float e = sc[tid];
#pragma unroll
            for (int off = 1; off < 64; off <<= 1) e += __shfl_xor(e, off);
            if (lane == 0) red[wid] = e;
        }

        // ---- partial context: 8 h x 4 l per thread, uint4 loads ----
        {
            const int hg = (tid & 31) << 3;
            const int lc = tid >> 5;           // 0..31
            float acc[8] = {0.f, 0.f, 0.f, 0.f, 0.f, 0.f, 0.f, 0.f};
#pragma unroll
            for (int i = 0; i < 4; ++i) {
                int ll = (lc << 2) + i;
                float e = sc[ll];
                const unsigned short* fb = F + (((size_t)(b * L_ + l0 + ll)) << 9) + hg;
                uint4 w = *(const uint4*)fb;
                acc[0] = fmaf(e, bf2f((unsigned short)(w.x & 0xffffu)), acc[0]);
                acc[1] = fmaf(e, bf2f((unsigned short)(w.x >> 16)),     acc[1]);
                acc[2] = fmaf(e, bf2f((unsigned short)(w.y & 0xffffu)), acc[2]);
                acc[3] = fmaf(e, bf2f((unsigned short)(w.y >> 16)),     acc[3]);
                acc[4] = fmaf(e, bf2f((unsigned short)(w.z & 0xffffu)), acc[4]);
                acc[5] = fmaf(e, bf2f((unsigned short)(w.z >> 16)),     acc[5]);
                acc[6] = fmaf(e, bf2f((unsigned short)(w.w & 0xffffu)), acc[6]);
                acc[7] = fmaf(e, bf2f((unsigned short)(w.w >> 16)),     acc[7]);
            }
            float* cp = &ctxp[(lc << 8) + hg];
            *(float4*)cp       = *(float4*)&acc[0];
            *(float4*)(cp + 4) = *(float4*)&acc[4];
        }
        __syncthreads();

        // ---- publish ctx partial + e-sum ----
        if (tid < 256) {
            float s2 = 0.0f;
#pragma unroll
            for (int c = 0; c < 32; ++c) s2 += ctxp[(c << 8) + tid];
            __hip_atomic_store(&myctx[sub * 256 + tid], s2, __ATOMIC_RELAXED, __HIP_MEMORY_SCOPE_AGENT);
        } else if (tid == 256) {
            __hip_atomic_store(&mysum[sub], red[0] + red[1], __ATOMIC_RELAXED, __HIP_MEMORY_SCOPE_AGENT);
        }

        ++nsync;
        batch_barrier(mybar, NSUB * nsync, tid);

        // ---- assemble full context + 1/S ----
        float s2 = 0.0f;
        if (tid < 256) {
#pragma unroll
            for (int s = 0; s < NSUB; ++s)
                s2 += __hip_atomic_load(&myctx[s * 256 + tid], __ATOMIC_RELAXED, __HIP_MEMORY_SCOPE_AGENT);
        } else if (tid == 256) {
            float S = 0.0f;
#pragma unroll
            for (int s = 0; s < NSUB; ++s)
                S += __hip_atomic_load(&mysum[s], __ATOMIC_RELAXED, __HIP_MEMORY_SCOPE_AGENT);
            red[16] = frcp(S);
        }
        __syncthreads();
        float rS = red[16];
        if (tid < 256) xv[256 + tid] = s2 * rS;
        if (tid < LSUB) cov[tid] += sc[tid] * rS;
        __syncthreads();

        // ---- GRU partial matvecs (K-split 8-way) ----
        if (tid < 384) {
            int o = tid << 1;
            float a0 = 0.0f, a1 = 0.0f;
            const unsigned short* wp = WihT + o;
            for (int k = kg0; k < kg1; ++k) {
                float x = xv[k];
                unsigned int w = *(const unsigned int*)(wp + (size_t)k * 768);
                a0 = fmaf(x, bf2f((unsigned short)(w & 0xffffu)), a0);
                a1 = fmaf(x, bf2f((unsigned short)(w >> 16)), a1);
            }
            __hip_atomic_store(&mygg[sub * 1536 + o],     a0, __ATOMIC_RELAXED, __HIP_MEMORY_SCOPE_AGENT);
            __hip_atomic_store(&mygg[sub * 1536 + o + 1], a1, __ATOMIC_RELAXED, __HIP_MEMORY_SCOPE_AGENT);
        } else if (tid < 768) {
            int o = (tid - 384) << 1;
            float a0 = 0.0f, a1 = 0.0f;
            const unsigned short* wp = WhhT + o;
            for (int k = kh0; k < kh0 + 32; ++k) {
                float x = hv[k];
                unsigned int w = *(const unsigned int*)(wp + (size_t)k * 768);
                a0 = fmaf(x, bf2f((unsigned short)(w & 0xffffu)), a0);
                a1 = fmaf(x, bf2f((unsigned short)(w >> 16)), a1);
            }
            __hip_atomic_store(&mygg[sub * 1536 + 768 + o],     a0, __ATOMIC_RELAXED, __HIP_MEMORY_SCOPE_AGENT);
            __hip_atomic_store(&mygg[sub * 1536 + 768 + o + 1], a1, __ATOMIC_RELAXED, __HIP_MEMORY_SCOPE_AGENT);
        }

        ++nsync;
        batch_barrier(mybar, NSUB * nsync, tid);

        // ---- reduce gi/gh (deterministic order -> identical h in all replicas) ----
        if (tid < 384) {
            int o = tid << 1;
            float v0 = bih[o], v1 = bih[o + 1];
#pragma unroll
            for (int s = 0; s < NSUB; ++s) {
                v0 += __hip_atomic_load(&mygg[s * 1536 + o],     __ATOMIC_RELAXED, __HIP_MEMORY_SCOPE_AGENT);
                v1 += __hip_atomic_load(&mygg[s * 1536 + o + 1], __ATOMIC_RELAXED, __HIP_MEMORY_SCOPE_AGENT);
            }
            gi[o] = v0; gi[o + 1] = v1;
        } else if (tid < 768) {
            int o = (tid - 384) << 1;
            float v0 = bhh[o], v1 = bhh[o + 1];
#pragma unroll
            for (int s = 0; s < NSUB; ++s) {
                v0 += __hip_atomic_load(&mygg[s * 1536 + 768 + o],     __ATOMIC_RELAXED, __HIP_MEMORY_SCOPE_AGENT);
                v1 += __hip_atomic_load(&mygg[s * 1536 + 768 + o + 1], __ATOMIC_RELAXED, __HIP_MEMORY_SCOPE_AGENT);
            }
            gh[o] = v0; gh[o + 1] = v1;
        }
        __syncthreads();

        // ---- gates + h update ; assemble xo=[h,ctx,cv] ----
        if (tid < 256) {
            float r = sig_fast(gi[tid] + gh[tid]);
            float z = sig_fast(gi[256 + tid] + gh[256 + tid]);
            float n = tanh_fast(fmaf(r, gh[512 + tid], gi[512 + tid]));
            float hold = hv[tid];
            float hn = (1.0f - z) * n + z * hold;
            hv[tid] = hn;
            hbs[tid] = hn + cov_b[tid];
            xo[tid] = hn;
        } else if (tid < KX_) {
            xo[tid] = xv[tid];
        }
        __syncthreads();

        // ---- output layer: this block's 14-class chunk ----
        {
            int c  = tid & 15;
            int kc = tid >> 4;
            int k0 = kc * 10;
            int k1 = k0 + 10; if (k1 > KX_) k1 = KX_;
            float a = 0.0f;
            for (int k = k0; k < k1; ++k)
                a = fmaf(xo[k], bf2f(WoutT[(size_t)k * 128 + cbase + c]), a);
            outp[(kc << 4) + c] = a;
        }
        __syncthreads();
        if (tid < ccnt) {
            float s3 = outb[cbase + tid];
#pragma unroll
            for (int i = 0; i < 64; ++i) s3 += outp[(i << 4) + tid];
            OUT[((size_t)b * T_ + t) * Cc_ + cbase + tid] = s3;
        }
        // no trailing sync needed: next-iteration writes are ordered behind barA/barB
    }
}

// ---------------- launch ----------------
extern "C" void kernel_launch(void* const* d_in, const int* in_sizes, int n_in,
                              void* d_out, int out_size, void* d_ws, size_t ws_size,
                              hipStream_t stream) {
    const float* fm      = (const float*)d_in[0];
    const float* cvv     = (const float*)d_in[1];
    const int*   tgt     = (const int*)d_in[2];
    const float* conv_w  = (const float*)d_in[3];
    const float* conv_b  = (const float*)d_in[4];
    const float* emb     = (const float*)d_in[5];
    const float* wih     = (const float*)d_in[6];
    const float* whh     = (const float*)d_in[7];
    const float* bih     = (const float*)d_in[8];
    const float* bhh     = (const float*)d_in[9];
    const float* attn_w  = (const float*)d_in[10];
    const float* attn_b  = (const float*)d_in[11];
    const float* attn_v  = (const float*)d_in[12];
    const float* attn_vb = (const float*)d_in[13];
    const float* cov_w   = (const float*)d_in[14];
    const float* cov_b   = (const float*)d_in[15];
    const float* outw    = (const float*)d_in[16];
    const float* outb    = (const float*)d_in[17];
    float* OUT = (float*)d_out;
    char* ws = (char*)d_ws;

    unsigned short* F     = (unsigned short*)(ws);                 // 67,108,864
    unsigned short* Wc    = (unsigned short*)(ws + 67108864);      //  1,048,576
    float*          biasC = (float*)(ws + 68157440);               //  2,097,152
    float*          PE    = (float*)(ws + 70254592);               //  2,097,152
    unsigned short* WihT  = (unsigned short*)(ws + 72351744);      //    956,928
    unsigned short* WhhT  = (unsigned short*)(ws + 73308672);      //    393,216
    unsigned short* WoutT = (unsigned short*)(ws + 73701888);      //    159,488

    // decoder scratch overlays Wc+biasC (dead after gemm_feats; rebuilt each launch)
    int*   bar  = (int*)(ws + 67108864);                           //   4 KB
    float* gsum = (float*)(ws + 67112960);                         //   2 KB [b][8]
    float* gctx = (float*)(ws + 67115008);                         // 512 KB [b][8][256]
    float* ggih = (float*)(ws + 67639296);                         // 3 MB  [b][8][1536]

    pe_kernel<<<2048, 256, 0, stream>>>(PE);
    wc_kernel<<<dim3(4, 512), 256, 0, stream>>>(conv_w, attn_w, Wc);
    biasf_kernel<<<1024, 256, 0, stream>>>(conv_b, PE, biasC);
    biasw_kernel<<<dim3(4, 256), 256, 0, stream>>>(conv_b, PE, attn_w, attn_b, biasC);
    wiht_kernel<<<1869, 256, 0, stream>>>(wih, WihT);
    whht_kernel<<<768, 256, 0, stream>>>(whh, WhhT);
    woutt_kernel<<<271, 256, 0, stream>>>(outw, WoutT);
    gemm_feats<<<dim3(512, 4), 256, 0, stream>>>(fm, Wc, biasC, F);
    zero_kernel<<<4, 256, 0, stream>>>(bar, 1024);
    decoder_kernel<<<512, 1024, 0, stream>>>(F, WihT, WhhT, WoutT,
        cvv, tgt, emb, bih, bhh, attn_v, attn_vb, cov_w, cov_b, outb,
        bar, gsum, gctx, ggih, OUT);
}